// Round 3
// baseline (108.580 us; speedup 1.0000x reference)
//
#include <hip/hip_runtime.h>
#include <math.h>

// Problem constants (from reference setup_inputs)
#define B     16
#define PDIM  2048
#define QDIM  2048

// Main-pass tiling: block = 512 threads = 8 waves, grid = NQB*NPC = 256 blocks
// (1 block/CU, 8 waves/CU).
//  - wave w owns batch pair {2w, 2w+1}  (b-split: single writer per (b,q))
//  - lane l owns 4 consecutive q (float4) -> 256 q per block
//  - block processes PCHUNK = 64 rows of W
#define NQB    8      // Q / 256
#define NPC    32     // P / PCHUNK
#define PCHUNK 64

// weight_changes is identically 0: an active STDP pair requires BOTH neurons
// to spike at current_time, forcing dts = 0, which satisfies neither
// (dts > 0) nor (dts < 0). So new_weights = clamp(weights, 0, 1), sc is a
// spike-masked column sum, and the B*P*Q tensor never needs to exist.
// This kernel also absorbs the trace decay (blocks 0..31) so the tail
// dispatch is the sc reduction only.
__global__ __launch_bounds__(512) void stdp_main(
    const float* __restrict__ pre_spikes,  // [B, P], values exactly {0.0, 1.0}
    const float* __restrict__ post_spikes, // [B, Q]
    const float* __restrict__ pre_trace,   // [B, P]
    const float* __restrict__ post_trace,  // [B, Q]
    const float* __restrict__ dtp,         // scalar dt
    const float* __restrict__ weights,     // [P, Q]
    float* __restrict__ nw,                // [P, Q]  clamp(W)
    float* __restrict__ wc,                // [P, Q]  zeros
    float* __restrict__ ws,                // [NPC, B, Q] partial column sums
    float* __restrict__ pre_o,             // [B, P]
    float* __restrict__ post_o)            // [B, Q]
{
    __shared__ float sp[PCHUNK][B];        // spikes, [p_local][b], 4 KB

    const int qb   = blockIdx.x & (NQB - 1);
    const int pc   = blockIdx.x >> 3;
    const int p0   = pc * PCHUNK;
    const int wave = threadIdx.x >> 6;     // 0..7
    const int lane = threadIdx.x & 63;
    const int q    = qb * 256 + lane * 4;
    const int b0   = wave * 2;

    // Fused trace decay: 16384 float4 elements total (pre 8192 + post 8192),
    // handled by the first 32 blocks (one float4 per thread, overlaps main).
    {
        const int t = blockIdx.x * 512 + threadIdx.x;
        if (t < 16384) {
            const float decay = expf(-dtp[0] * 50.0f);   // 1/TAU == 50
            if (t < 8192) {
                const float4 s = ((const float4*)pre_spikes)[t];
                const float4 r = ((const float4*)pre_trace)[t];
                float4 o;
                o.x = fmaf(r.x, decay, s.x); o.y = fmaf(r.y, decay, s.y);
                o.z = fmaf(r.z, decay, s.z); o.w = fmaf(r.w, decay, s.w);
                ((float4*)pre_o)[t] = o;
            } else {
                const int u = t - 8192;
                const float4 s = ((const float4*)post_spikes)[u];
                const float4 r = ((const float4*)post_trace)[u];
                float4 o;
                o.x = fmaf(r.x, decay, s.x); o.y = fmaf(r.y, decay, s.y);
                o.z = fmaf(r.z, decay, s.z); o.w = fmaf(r.w, decay, s.w);
                ((float4*)post_o)[u] = o;
            }
        }
    }

    // Stage this chunk's spike values (PCHUNK*B = 1024 floats), coalesced.
    for (int t = threadIdx.x; t < B * PCHUNK; t += 512) {
        const int b  = t >> 6;             // PCHUNK == 64
        const int pl = t & (PCHUNK - 1);
        sp[pl][b] = pre_spikes[b * PDIM + p0 + pl];
    }
    __syncthreads();

    float4 acc0 = {0,0,0,0}, acc1 = {0,0,0,0};

    const size_t base = (size_t)p0 * QDIM + q;
    const float* __restrict__ wp  = weights + base;
    float* __restrict__       nwp = nw + base;
    float* __restrict__       wcp = wc + base;

    #pragma unroll 8
    for (int i = 0; i < PCHUNK; ++i) {
        const float4 w = *(const float4*)(wp + (size_t)i * QDIM);   // 16 B/lane
        // wave-uniform ds_read_b64 -> broadcast, conflict-free
        const float2 s = *(const float2*)&sp[i][b0];

        acc0.x = fmaf(s.x, w.x, acc0.x); acc0.y = fmaf(s.x, w.y, acc0.y);
        acc0.z = fmaf(s.x, w.z, acc0.z); acc0.w = fmaf(s.x, w.w, acc0.w);
        acc1.x = fmaf(s.y, w.x, acc1.x); acc1.y = fmaf(s.y, w.y, acc1.y);
        acc1.z = fmaf(s.y, w.z, acc1.z); acc1.w = fmaf(s.y, w.w, acc1.w);

        if (wave == 0) {                   // wave-uniform branch
            float4 c;
            c.x = fminf(fmaxf(w.x, 0.0f), 1.0f);
            c.y = fminf(fmaxf(w.y, 0.0f), 1.0f);
            c.z = fminf(fmaxf(w.z, 0.0f), 1.0f);
            c.w = fminf(fmaxf(w.w, 0.0f), 1.0f);
            *(float4*)(nwp + (size_t)i * QDIM) = c;
        } else if (wave == 1) {
            const float4 z = {0,0,0,0};
            *(float4*)(wcp + (size_t)i * QDIM) = z;
        }
    }

    // Partial column sums: ws[pc][b][q], exactly one writer per element
    // (no atomics, no pre-zero needed -> poison-safe, deterministic).
    float* __restrict__ wsp = ws + ((size_t)(pc * B + b0)) * QDIM + q;
    *(float4*)(wsp + 0 * (size_t)QDIM) = acc0;
    *(float4*)(wsp + 1 * (size_t)QDIM) = acc1;
}

// sc reduction over the NPC partial slabs. 8192 float4 outputs; grid
// 128 blocks x 64 threads (1 wave each, 128 CUs active). Full unroll keeps
// ~31 b128 loads in flight per wave -> the whole 4.2 MB buffer is in flight.
__global__ __launch_bounds__(64) void stdp_screduce(
    const float* __restrict__ ws,       // [NPC, B, Q]
    float* __restrict__ sc)             // [B, Q]
{
    const int u  = blockIdx.x * 64 + threadIdx.x;   // < 8192
    const int b  = u >> 9;                          // QDIM/4 == 512
    const int qc = (u & 511) << 2;
    const float* __restrict__ p = ws + (size_t)b * QDIM + qc;
    float4 s = {0,0,0,0};
    #pragma unroll
    for (int pc = 0; pc < NPC; ++pc) {
        const float4 v = *(const float4*)(p + (size_t)pc * B * QDIM);
        s.x += v.x; s.y += v.y; s.z += v.z; s.w += v.w;
    }
    *(float4*)(sc + (size_t)b * QDIM + qc) = s;
}

extern "C" void kernel_launch(void* const* d_in, const int* in_sizes, int n_in,
                              void* d_out, int out_size, void* d_ws, size_t ws_size,
                              hipStream_t stream) {
    // Input order: pre_spikes, post_spikes, weights, pre_trace, post_trace,
    // last_pre_spike, last_post_spike, current_time, dt
    // (last_*_spike / current_time provably unused — see stdp_main comment)
    const float* pre_spikes  = (const float*)d_in[0];
    const float* post_spikes = (const float*)d_in[1];
    const float* weights     = (const float*)d_in[2];
    const float* pre_trace   = (const float*)d_in[3];
    const float* post_trace  = (const float*)d_in[4];
    const float* dtp         = (const float*)d_in[8];

    // Output layout (flat, return order):
    //   synaptic_current [B,Q], weight_changes [P,Q] (==0),
    //   pre_trace_new [B,P], post_trace_new [B,Q], new_weights [P,Q]
    float* out    = (float*)d_out;
    float* sc     = out;
    float* wc     = out + (size_t)B * QDIM;
    float* pre_o  = wc  + (size_t)PDIM * QDIM;
    float* post_o = pre_o + (size_t)B * PDIM;
    float* nw     = post_o + (size_t)B * QDIM;

    float* ws = (float*)d_ws;   // NPC*B*Q*4 = 4.2 MB, fully overwritten before read

    stdp_main<<<dim3(NQB * NPC), dim3(512), 0, stream>>>(
        pre_spikes, post_spikes, pre_trace, post_trace, dtp, weights,
        nw, wc, ws, pre_o, post_o);

    stdp_screduce<<<dim3(128), dim3(64), 0, stream>>>(ws, sc);
}

// Round 4
// 101.969 us; speedup vs baseline: 1.0648x; 1.0648x over previous
//
#include <hip/hip_runtime.h>
#include <math.h>

// Problem constants (from reference setup_inputs)
#define B     16
#define PDIM  2048
#define QDIM  2048

// Main-pass tiling (round-2 measured-best shape): block = 256 threads = 4
// waves, grid = NQB*NPC = 512 blocks -> 2 blocks/CU, 8 waves/CU.
//  - wave w owns batches [4w, 4w+4)   (b-split: single writer per (b,q))
//  - lane l owns 4 consecutive q (float4) -> 256 q per block
//  - block processes PCHUNK = 32 rows of W
#define NQB    8      // Q / 256
#define NPC    64     // P / PCHUNK
#define PCHUNK 32

// weight_changes is identically 0: an active STDP pair requires BOTH neurons
// to spike at current_time, forcing dts = 0, which satisfies neither
// (dts > 0) nor (dts < 0). So new_weights = clamp(weights, 0, 1), sc is a
// spike-masked column sum (pre_spikes are exactly {0,1}), and the B*P*Q
// tensor never needs to exist. Streaming pass over W: read 16.8 MB, write
// nw (16.8) + wc zeros (16.8) + ws partials (8.4).
__global__ __launch_bounds__(256) void stdp_main(
    const float* __restrict__ pre_spikes,  // [B, P], values exactly {0.0, 1.0}
    const float* __restrict__ weights,     // [P, Q]
    float* __restrict__ nw,                // [P, Q]  clamp(W)
    float* __restrict__ wc,                // [P, Q]  zeros
    float* __restrict__ ws)                // [NPC, B, Q] partial column sums
{
    __shared__ float sp[PCHUNK][B];        // spikes, [p_local][b], 2 KB

    const int qb   = blockIdx.x & (NQB - 1);
    const int pc   = blockIdx.x >> 3;
    const int p0   = pc * PCHUNK;
    const int wave = threadIdx.x >> 6;     // 0..3
    const int lane = threadIdx.x & 63;
    const int q    = qb * 256 + lane * 4;
    const int b0   = wave * 4;

    // Stage this chunk's spike values (512 floats), coalesced in 32-lane runs.
    for (int t = threadIdx.x; t < B * PCHUNK; t += 256) {
        const int b  = t >> 5;             // PCHUNK == 32
        const int pl = t & (PCHUNK - 1);
        sp[pl][b] = pre_spikes[b * PDIM + p0 + pl];
    }
    __syncthreads();

    float4 acc0 = {0,0,0,0}, acc1 = {0,0,0,0}, acc2 = {0,0,0,0}, acc3 = {0,0,0,0};

    const size_t base = (size_t)p0 * QDIM + q;
    const float* __restrict__ wp  = weights + base;
    float* __restrict__       nwp = nw + base;
    float* __restrict__       wcp = wc + base;

    #pragma unroll 8
    for (int i = 0; i < PCHUNK; ++i) {
        const float4 w = *(const float4*)(wp + (size_t)i * QDIM);   // 16 B/lane
        // wave-uniform ds_read_b128 -> broadcast, conflict-free
        const float4 s = *(const float4*)&sp[i][b0];

        acc0.x = fmaf(s.x, w.x, acc0.x); acc0.y = fmaf(s.x, w.y, acc0.y);
        acc0.z = fmaf(s.x, w.z, acc0.z); acc0.w = fmaf(s.x, w.w, acc0.w);
        acc1.x = fmaf(s.y, w.x, acc1.x); acc1.y = fmaf(s.y, w.y, acc1.y);
        acc1.z = fmaf(s.y, w.z, acc1.z); acc1.w = fmaf(s.y, w.w, acc1.w);
        acc2.x = fmaf(s.z, w.x, acc2.x); acc2.y = fmaf(s.z, w.y, acc2.y);
        acc2.z = fmaf(s.z, w.z, acc2.z); acc2.w = fmaf(s.z, w.w, acc2.w);
        acc3.x = fmaf(s.w, w.x, acc3.x); acc3.y = fmaf(s.w, w.y, acc3.y);
        acc3.z = fmaf(s.w, w.z, acc3.z); acc3.w = fmaf(s.w, w.w, acc3.w);

        if (wave == 0) {                   // wave-uniform branch (s_cbranch)
            float4 c;
            c.x = fminf(fmaxf(w.x, 0.0f), 1.0f);
            c.y = fminf(fmaxf(w.y, 0.0f), 1.0f);
            c.z = fminf(fmaxf(w.z, 0.0f), 1.0f);
            c.w = fminf(fmaxf(w.w, 0.0f), 1.0f);
            *(float4*)(nwp + (size_t)i * QDIM) = c;
        } else if (wave == 1) {
            const float4 z = {0,0,0,0};
            *(float4*)(wcp + (size_t)i * QDIM) = z;
        }
    }

    // Partial column sums: ws[pc][b][q], exactly one writer per element
    // (no atomics, no pre-zero needed -> poison-safe, deterministic).
    float* __restrict__ wsp = ws + ((size_t)(pc * B + b0)) * QDIM + q;
    *(float4*)(wsp + 0 * (size_t)QDIM) = acc0;
    *(float4*)(wsp + 1 * (size_t)QDIM) = acc1;
    *(float4*)(wsp + 2 * (size_t)QDIM) = acc2;
    *(float4*)(wsp + 3 * (size_t)QDIM) = acc3;
}

// Tail, one dispatch spread over 384 small blocks (covers 256+ CUs):
//  - blocks 0..127  : sc reduction over the NPC partial slabs; one float4
//    output per thread, fully unrolled 64-deep -> ~60 b128 loads in flight
//    per wave, whole 8.4 MB buffer in flight across 128 CUs.
//  - blocks 128..383: trace decay, one float4 per thread (pre 8192 + post
//    8192 float4 elements).
__global__ __launch_bounds__(64) void stdp_tail(
    const float* __restrict__ ws,       // [NPC, B, Q]
    const float* __restrict__ pre_s,
    const float* __restrict__ post_s,
    const float* __restrict__ pre_t,
    const float* __restrict__ post_t,
    const float* __restrict__ dtp,      // scalar dt on device
    float* __restrict__ sc,             // [B, Q]
    float* __restrict__ pre_o,
    float* __restrict__ post_o)
{
    if (blockIdx.x < 128) {
        const int u  = blockIdx.x * 64 + threadIdx.x;   // < 8192
        const int b  = u >> 9;                          // QDIM/4 == 512
        const int qc = (u & 511) << 2;
        const float* __restrict__ p = ws + (size_t)b * QDIM + qc;
        float4 s = {0,0,0,0};
        #pragma unroll
        for (int pc = 0; pc < NPC; ++pc) {
            const float4 v = *(const float4*)(p + (size_t)pc * B * QDIM);
            s.x += v.x; s.y += v.y; s.z += v.z; s.w += v.w;
        }
        *(float4*)(sc + (size_t)b * QDIM + qc) = s;
    } else {
        const int t = (blockIdx.x - 128) * 64 + threadIdx.x;  // < 16384
        const float decay = expf(-dtp[0] * 50.0f);            // 1/TAU == 50
        if (t < 8192) {
            const float4 s = ((const float4*)pre_s)[t];
            const float4 r = ((const float4*)pre_t)[t];
            float4 o;
            o.x = fmaf(r.x, decay, s.x); o.y = fmaf(r.y, decay, s.y);
            o.z = fmaf(r.z, decay, s.z); o.w = fmaf(r.w, decay, s.w);
            ((float4*)pre_o)[t] = o;
        } else {
            const int u = t - 8192;
            const float4 s = ((const float4*)post_s)[u];
            const float4 r = ((const float4*)post_t)[u];
            float4 o;
            o.x = fmaf(r.x, decay, s.x); o.y = fmaf(r.y, decay, s.y);
            o.z = fmaf(r.z, decay, s.z); o.w = fmaf(r.w, decay, s.w);
            ((float4*)post_o)[u] = o;
        }
    }
}

extern "C" void kernel_launch(void* const* d_in, const int* in_sizes, int n_in,
                              void* d_out, int out_size, void* d_ws, size_t ws_size,
                              hipStream_t stream) {
    // Input order: pre_spikes, post_spikes, weights, pre_trace, post_trace,
    // last_pre_spike, last_post_spike, current_time, dt
    // (last_*_spike / current_time provably unused — see stdp_main comment)
    const float* pre_spikes  = (const float*)d_in[0];
    const float* post_spikes = (const float*)d_in[1];
    const float* weights     = (const float*)d_in[2];
    const float* pre_trace   = (const float*)d_in[3];
    const float* post_trace  = (const float*)d_in[4];
    const float* dtp         = (const float*)d_in[8];

    // Output layout (flat, return order):
    //   synaptic_current [B,Q], weight_changes [P,Q] (==0),
    //   pre_trace_new [B,P], post_trace_new [B,Q], new_weights [P,Q]
    float* out    = (float*)d_out;
    float* sc     = out;
    float* wc     = out + (size_t)B * QDIM;
    float* pre_o  = wc  + (size_t)PDIM * QDIM;
    float* post_o = pre_o + (size_t)B * PDIM;
    float* nw     = post_o + (size_t)B * QDIM;

    float* ws = (float*)d_ws;   // NPC*B*Q*4 = 8.4 MB, fully overwritten before read

    stdp_main<<<dim3(NQB * NPC), dim3(256), 0, stream>>>(
        pre_spikes, weights, nw, wc, ws);

    stdp_tail<<<dim3(384), dim3(64), 0, stream>>>(
        ws, pre_spikes, post_spikes, pre_trace, post_trace, dtp,
        sc, pre_o, post_o);
}